// Round 2
// baseline (141.631 us; speedup 1.0000x reference)
//
#include <hip/hip_runtime.h>

typedef __attribute__((ext_vector_type(8))) short bf16x8;
typedef __attribute__((ext_vector_type(4))) float f32x4;

#define MDIM 256
#define NDIM 4096
#define KDIM 4096
#define NGRP 32
#define BM 128
#define BN 32
#define BK 64
#define NT (KDIM / BK) /* 64 */

typedef const __attribute__((address_space(1))) void* gas_ptr;
typedef __attribute__((address_space(3))) void* las_ptr;

__device__ __forceinline__ unsigned short f2bf(float f) {
  union { float f; unsigned int u; } v;
  v.f = f;
  unsigned int r = v.u + 0x7FFFu + ((v.u >> 16) & 1u); // RNE
  return (unsigned short)(r >> 16);
}

__device__ __forceinline__ void gl_lds16(const void* g, void* l) {
  __builtin_amdgcn_global_load_lds((gas_ptr)g, (las_ptr)l, 16, 0, 0);
}

__global__ void convA_kernel(const float* __restrict__ A,
                             unsigned short* __restrict__ Ab) {
  int i = blockIdx.x * 256 + threadIdx.x; // exactly M*K/4 threads
  float4 v = reinterpret_cast<const float4*>(A)[i];
  ushort4 o;
  o.x = f2bf(v.x); o.y = f2bf(v.y); o.z = f2bf(v.z); o.w = f2bf(v.w);
  reinterpret_cast<ushort4*>(Ab)[i] = o;
}

__global__ __launch_bounds__(256, 1) void gemm_kernel(
    const unsigned short* __restrict__ Ab, const int* __restrict__ qw,
    const float* __restrict__ sc, const float* __restrict__ zr,
    float* __restrict__ out) {
  __shared__ __align__(16) unsigned short A_lds[4][BM * BK]; // 64 KB, 4-deep
  __shared__ __align__(16) unsigned short W_lds[2][BN * BK]; // 8 KB
  __shared__ float s_lds[BN * NGRP];   // s
  __shared__ float zs_lds[BN * NGRP];  // z*s

  const int tid = threadIdx.x;
  const int lane = tid & 63;
  const int wave = tid >> 6;
  const int wm = wave >> 1; // 0..1 -> 64 rows each
  const int wn = wave & 1;  // 0..1 -> 16 cols each

  // XCD-bijective swizzle: pair both M-halves of one N-range on one XCD.
  const int bid = blockIdx.x;            // grid = 256, 256 % 8 == 0
  const int swz = (bid & 7) * 32 + (bid >> 3);
  const int m0 = (swz & 1) * BM;
  const int n0 = (swz >> 1) * BN;

  // stage scales and z*s for this block's 32 n-rows, all 32 groups
  for (int i = tid; i < BN * NGRP; i += 256) {
    int n = i >> 5;
    int g = i & 31;
    float s = sc[(size_t)(n0 + n) * NGRP + g];
    float z = zr[(size_t)(n0 + n) * NGRP + g];
    s_lds[i] = s;
    zs_lds[i] = z * s;
  }

  const unsigned short* Abase = Ab + (size_t)m0 * KDIM;
  const int wrow = tid >> 3; // 0..31 (n-row for W staging)
  const int wc = tid & 7;    // 16B chunk within 64-k row
  const int* qbase = qw + (size_t)(n0 + wrow) * KDIM + wc * 8;

  int4 qr[4][2]; // all indices compile-time after unroll -> registers

  auto loadW = [&](int t, int idx) {
    const int* p = qbase + t * BK;
    qr[idx][0] = *reinterpret_cast<const int4*>(p);
    qr[idx][1] = *reinterpret_cast<const int4*>(p + 4);
  };
  // A tile 128x64 bf16 = 1024 x 16B chunks; linear LDS dest (gload_lds),
  // XOR-swizzled global SOURCE so reads can use swizzled addresses (rule 21).
  auto stageA = [&](int t, int b) {
#pragma unroll
    for (int i = 0; i < 4; ++i) {
      int cid = i * 256 + tid;
      int row = cid >> 3;
      int cp = cid & 7;
      int cs = cp ^ (row & 7);
      const unsigned short* g = Abase + (size_t)row * KDIM + t * BK + cs * 8;
      gl_lds16(g, &A_lds[b][(i * 256 + wave * 64) * 8]); // wave-uniform base
    }
  };
  auto writeW = [&](int t, int b, int idx) {
    int gg = t >> 1; // BK=64 fits in one 128-group; g uniform per step
    float s = s_lds[wrow * NGRP + gg];
    float zs = zs_lds[wrow * NGRP + gg];
    int q[8] = {qr[idx][0].x, qr[idx][0].y, qr[idx][0].z, qr[idx][0].w,
                qr[idx][1].x, qr[idx][1].y, qr[idx][1].z, qr[idx][1].w};
    bf16x8 w;
#pragma unroll
    for (int j = 0; j < 8; ++j)
      w[j] = (short)f2bf(fmaf((float)q[j], s, -zs));
    *reinterpret_cast<bf16x8*>(
        &W_lds[b][wrow * BK + ((wc ^ (wrow & 7)) << 3)]) = w;
  };

  f32x4 acc[4];
#pragma unroll
  for (int i = 0; i < 4; ++i) acc[i] = (f32x4){0.f, 0.f, 0.f, 0.f};

  const int l15 = lane & 15;
  const int lhi = lane >> 4;
  const int ar0 = wm * 64 + l15;
  const int asw = ar0 & 7;
  const int br = wn * 16 + l15;
  const int bsw = br & 7;

  auto compute = [&](int ab, int wb) {
#pragma unroll
    for (int ks = 0; ks < 2; ++ks) {
      bf16x8 bfr = *reinterpret_cast<const bf16x8*>(
          &W_lds[wb][br * BK + ((((ks << 2) + lhi) ^ bsw) << 3)]);
#pragma unroll
      for (int mi = 0; mi < 4; ++mi) {
        bf16x8 afr = *reinterpret_cast<const bf16x8*>(
            &A_lds[ab][(ar0 + mi * 16) * BK + ((((ks << 2) + lhi) ^ asw) << 3)]);
        acc[mi] = __builtin_amdgcn_mfma_f32_16x16x32_bf16(afr, bfr, acc[mi], 0, 0, 0);
      }
    }
  };

  // ---- prologue: issue batches for t = 0,1,2 (6 vmem ops each) ----
  loadW(0, 0); stageA(0, 0);
  loadW(1, 1); stageA(1, 1);
  loadW(2, 2); stageA(2, 2);

  asm volatile("s_waitcnt lgkmcnt(0)" ::: "memory"); // my s/zs stores done
  __builtin_amdgcn_s_barrier();                      // s_lds/zs_lds visible
  __builtin_amdgcn_sched_barrier(0);
  writeW(0, 0, 0); // compiler inserts precise vmcnt for qr[0]
  asm volatile("s_waitcnt vmcnt(12) lgkmcnt(0)" ::: "memory"); // batch0 done
  __builtin_amdgcn_s_barrier();                      // A(0), W(0) ready
  __builtin_amdgcn_sched_barrier(0);

  // ---- main loop: 3-deep prefetch, never drain vmcnt to 0 ----
  for (int tb = 0; tb < NT; tb += 4) {
#pragma unroll
    for (int u = 0; u < 4; ++u) {
      const int t = tb + u;
      const int tp = (t + 3 < NT) ? (t + 3) : 0; // dummy keeps counts exact
      loadW(tp, (u + 3) & 3);
      stageA(tp, (u + 3) & 3);
      compute(u, u & 1);
      if (t + 1 < NT) writeW(t + 1, (u + 1) & 1, (u + 1) & 3);
      // drain batch t-2 only: guarantees A(t+1)/W-regs ready, leaves 12 in flight
      asm volatile("s_waitcnt vmcnt(12) lgkmcnt(0)" ::: "memory");
      __builtin_amdgcn_s_barrier();
      __builtin_amdgcn_sched_barrier(0);
    }
  }

  // ---- epilogue: C/D layout col=lane&15, row=(lane>>4)*4+j ----
  const int col = n0 + wn * 16 + l15;
  const int rb = m0 + wm * 64 + (lhi << 2);
#pragma unroll
  for (int mi = 0; mi < 4; ++mi)
#pragma unroll
    for (int j = 0; j < 4; ++j)
      out[(size_t)(rb + mi * 16 + j) * NDIM + col] = acc[mi][j];
}

extern "C" void kernel_launch(void* const* d_in, const int* in_sizes, int n_in,
                              void* d_out, int out_size, void* d_ws, size_t ws_size,
                              hipStream_t stream) {
  const float* A = (const float*)d_in[0];
  const int* qw = (const int*)d_in[1];
  const float* sc = (const float*)d_in[2];
  const float* zr = (const float*)d_in[3];
  float* out = (float*)d_out;
  unsigned short* Ab = (unsigned short*)d_ws; // 2 MB bf16 copy of A

  convA_kernel<<<(MDIM * KDIM / 4) / 256, 256, 0, stream>>>(A, Ab);
  gemm_kernel<<<(MDIM / BM) * (NDIM / BN), 256, 0, stream>>>(Ab, qw, sc, zr, out);
}

// Round 3
// 136.939 us; speedup vs baseline: 1.0343x; 1.0343x over previous
//
#include <hip/hip_runtime.h>

typedef __attribute__((ext_vector_type(8))) short bf16x8;
typedef __attribute__((ext_vector_type(4))) float f32x4;

#define MDIM 256
#define NDIM 4096
#define KDIM 4096
#define NGRP 32
#define BM 128
#define BN 32
#define BK 64
#define SPLITK 2
#define KLOC (KDIM / SPLITK) /* 2048 */
#define NTL (KLOC / BK)      /* 32 local tiles */

typedef const __attribute__((address_space(1))) void* gas_ptr;
typedef __attribute__((address_space(3))) void* las_ptr;

__device__ __forceinline__ unsigned short f2bf(float f) {
  union { float f; unsigned int u; } v;
  v.f = f;
  unsigned int r = v.u + 0x7FFFu + ((v.u >> 16) & 1u); // RNE
  return (unsigned short)(r >> 16);
}

__device__ __forceinline__ void gl_lds16(const void* g, void* l) {
  __builtin_amdgcn_global_load_lds((gas_ptr)g, (las_ptr)l, 16, 0, 0);
}

__global__ void convA_kernel(const float* __restrict__ A,
                             unsigned short* __restrict__ Ab) {
  int i = blockIdx.x * 256 + threadIdx.x; // exactly M*K/4 threads
  float4 v = reinterpret_cast<const float4*>(A)[i];
  ushort4 o;
  o.x = f2bf(v.x); o.y = f2bf(v.y); o.z = f2bf(v.z); o.w = f2bf(v.w);
  reinterpret_cast<ushort4*>(Ab)[i] = o;
}

__global__ __launch_bounds__(256, 2) void gemm_kernel(
    const unsigned short* __restrict__ Ab, const int* __restrict__ qw,
    const float* __restrict__ sc, const float* __restrict__ zr,
    float* __restrict__ out) {
  __shared__ __align__(16) unsigned short A_lds[4][BM * BK]; // 64 KB, 4-deep
  __shared__ __align__(16) unsigned short W_lds[2][BN * BK]; // 8 KB
  __shared__ float s_lds[BN * 16];   // s   (this split's 16 groups) 2 KB
  __shared__ float zs_lds[BN * 16];  // z*s                          2 KB
  // total 76 KB -> 2 blocks/CU (152 KB <= 160 KB)

  const int tid = threadIdx.x;
  const int lane = tid & 63;
  const int wave = tid >> 6;
  const int wm = wave >> 1; // 0..1 -> 64 rows each
  const int wn = wave & 1;  // 0..1 -> 16 cols each

  // XCD-bijective swizzle: all 4 blocks of one n-range (2 m-halves x 2 k-splits)
  // land on the same XCD so qweight is HBM-fetched once, L2-hit 3x.
  const int bid = blockIdx.x;        // grid = 512, 512 % 8 == 0
  const int x = bid & 7;             // XCD
  const int j = bid >> 3;            // 0..63 within XCD
  const int r = x * 16 + (j >> 2);   // n-range 0..127
  const int c = j & 3;               // which of the 4 sibling blocks
  const int m0 = (c & 1) * BM;
  const int ks = c >> 1;             // k-split 0..1
  const int n0 = r * BN;

  // stage s and z*s for this block's 32 n-rows, this split's 16 groups
  for (int i = tid; i < BN * 16; i += 256) {
    int n = i >> 4;
    int g16 = i & 15;
    float s = sc[(size_t)(n0 + n) * NGRP + ks * 16 + g16];
    float z = zr[(size_t)(n0 + n) * NGRP + ks * 16 + g16];
    s_lds[i] = s;
    zs_lds[i] = z * s;
  }

  const unsigned short* Abase = Ab + (size_t)m0 * KDIM + ks * KLOC;
  const int wrow = tid >> 3; // 0..31 (n-row for W staging)
  const int wc = tid & 7;    // 16B chunk within 64-k row
  const int* qbase = qw + (size_t)(n0 + wrow) * KDIM + ks * KLOC + wc * 8;

  int4 qr[4][2]; // all indices compile-time after unroll -> registers

  auto loadW = [&](int t, int idx) {
    const int* p = qbase + t * BK;
    qr[idx][0] = *reinterpret_cast<const int4*>(p);
    qr[idx][1] = *reinterpret_cast<const int4*>(p + 4);
  };
  // A tile 128x64 bf16 = 1024 x 16B chunks; linear LDS dest (gload_lds),
  // XOR-swizzled global SOURCE so reads can use swizzled addresses (rule 21).
  auto stageA = [&](int t, int b) {
#pragma unroll
    for (int i = 0; i < 4; ++i) {
      int cid = i * 256 + tid;
      int row = cid >> 3;
      int cp = cid & 7;
      int cs = cp ^ (row & 7);
      const unsigned short* g = Abase + (size_t)row * KDIM + t * BK + cs * 8;
      gl_lds16(g, &A_lds[b][(i * 256 + wave * 64) * 8]); // wave-uniform base
    }
  };
  auto writeW = [&](int t, int b, int idx) {
    int gg = t >> 1; // local group within split (BK=64, group=128)
    float s = s_lds[wrow * 16 + gg];
    float zs = zs_lds[wrow * 16 + gg];
    int q[8] = {qr[idx][0].x, qr[idx][0].y, qr[idx][0].z, qr[idx][0].w,
                qr[idx][1].x, qr[idx][1].y, qr[idx][1].z, qr[idx][1].w};
    bf16x8 w;
#pragma unroll
    for (int jj = 0; jj < 8; ++jj)
      w[jj] = (short)f2bf(fmaf((float)q[jj], s, -zs));
    *reinterpret_cast<bf16x8*>(
        &W_lds[b][wrow * BK + ((wc ^ (wrow & 7)) << 3)]) = w;
  };

  f32x4 acc[4];
#pragma unroll
  for (int i = 0; i < 4; ++i) acc[i] = (f32x4){0.f, 0.f, 0.f, 0.f};

  const int l15 = lane & 15;
  const int lhi = lane >> 4;
  const int ar0 = wm * 64 + l15;
  const int asw = ar0 & 7;
  const int br = wn * 16 + l15;
  const int bsw = br & 7;

  auto compute = [&](int ab, int wb) {
#pragma unroll
    for (int kss = 0; kss < 2; ++kss) {
      bf16x8 bfr = *reinterpret_cast<const bf16x8*>(
          &W_lds[wb][br * BK + ((((kss << 2) + lhi) ^ bsw) << 3)]);
#pragma unroll
      for (int mi = 0; mi < 4; ++mi) {
        bf16x8 afr = *reinterpret_cast<const bf16x8*>(
            &A_lds[ab][(ar0 + mi * 16) * BK + ((((kss << 2) + lhi) ^ asw) << 3)]);
        acc[mi] = __builtin_amdgcn_mfma_f32_16x16x32_bf16(afr, bfr, acc[mi], 0, 0, 0);
      }
    }
  };

  // ---- prologue: issue batches for t = 0,1,2 (6 vmem ops each) ----
  loadW(0, 0); stageA(0, 0);
  loadW(1, 1); stageA(1, 1);
  loadW(2, 2); stageA(2, 2);

  asm volatile("s_waitcnt lgkmcnt(0)" ::: "memory"); // my s/zs stores done
  __builtin_amdgcn_s_barrier();                      // s_lds/zs_lds visible
  __builtin_amdgcn_sched_barrier(0);
  writeW(0, 0, 0); // compiler inserts precise vmcnt for qr[0]
  asm volatile("s_waitcnt vmcnt(12) lgkmcnt(0)" ::: "memory"); // batch0 done
  __builtin_amdgcn_s_barrier();                      // A(0), W(0) ready
  __builtin_amdgcn_sched_barrier(0);

  // ---- main loop: 3-deep prefetch, never drain vmcnt to 0 ----
  for (int tb = 0; tb < NTL; tb += 4) {
#pragma unroll
    for (int u = 0; u < 4; ++u) {
      const int t = tb + u;
      const int tp = (t + 3 < NTL) ? (t + 3) : 0; // dummy keeps counts exact
      loadW(tp, (u + 3) & 3);
      stageA(tp, (u + 3) & 3);
      compute(u, u & 1);
      if (t + 1 < NTL) writeW(t + 1, (u + 1) & 1, (u + 1) & 3);
      // drain batch t+1's staging only: leaves 12 in flight
      asm volatile("s_waitcnt vmcnt(12) lgkmcnt(0)" ::: "memory");
      __builtin_amdgcn_s_barrier();
      __builtin_amdgcn_sched_barrier(0);
    }
  }

  // ---- epilogue: C/D layout col=lane&15, row=(lane>>4)*4+j; split-K adds ----
  const int col = n0 + wn * 16 + l15;
  const int rb = m0 + wm * 64 + (lhi << 2);
#pragma unroll
  for (int mi = 0; mi < 4; ++mi)
#pragma unroll
    for (int jj = 0; jj < 4; ++jj)
      unsafeAtomicAdd(&out[(size_t)(rb + mi * 16 + jj) * NDIM + col],
                      acc[mi][jj]);
}

extern "C" void kernel_launch(void* const* d_in, const int* in_sizes, int n_in,
                              void* d_out, int out_size, void* d_ws, size_t ws_size,
                              hipStream_t stream) {
  const float* A = (const float*)d_in[0];
  const int* qw = (const int*)d_in[1];
  const float* sc = (const float*)d_in[2];
  const float* zr = (const float*)d_in[3];
  float* out = (float*)d_out;
  unsigned short* Ab = (unsigned short*)d_ws; // 2 MB bf16 copy of A

  hipMemsetAsync(d_out, 0, (size_t)MDIM * NDIM * sizeof(float), stream);
  convA_kernel<<<(MDIM * KDIM / 4) / 256, 256, 0, stream>>>(A, Ab);
  gemm_kernel<<<(MDIM / BM) * (NDIM / BN) * SPLITK, 256, 0, stream>>>(
      Ab, qw, sc, zr, out);
}

// Round 7
// 134.542 us; speedup vs baseline: 1.0527x; 1.0178x over previous
//
#include <hip/hip_runtime.h>

typedef __attribute__((ext_vector_type(8))) short bf16x8;
typedef __attribute__((ext_vector_type(4))) float f32x4;

#define MDIM 256
#define NDIM 4096
#define KDIM 4096
#define KP8 (KDIM / 8) /* 512 packed dwords per n-row */
#define NGRP 32
#define BM 128
#define BN 32
#define BK 64
#define SPLITK 2
#define KLOC (KDIM / SPLITK) /* 2048 */
#define NTL (KLOC / BK)      /* 32 local tiles */

typedef const __attribute__((address_space(1))) void* gas_ptr;
typedef __attribute__((address_space(3))) void* las_ptr;

__device__ __forceinline__ unsigned short f2bf(float f) {
  union { float f; unsigned int u; } v;
  v.f = f;
  unsigned int r = v.u + 0x7FFFu + ((v.u >> 16) & 1u); // RNE
  return (unsigned short)(r >> 16);
}

__device__ __forceinline__ void gl_lds16(const void* g, void* l) {
  __builtin_amdgcn_global_load_lds((gas_ptr)g, (las_ptr)l, 16, 0, 0);
}

// ---------------- prep: pack q to nibbles (64->8 MB) + A fp32->bf16 ----------
__global__ void prep_kernel(const float* __restrict__ A, const int* __restrict__ q,
                            unsigned short* __restrict__ Ab,
                            unsigned int* __restrict__ qp) {
  int i = blockIdx.x * 256 + threadIdx.x; // grid 9216*256 = 2359296 exact
  if (i < NDIM * KP8) { // 2097152 pack threads, 32B in / 4B out
    const int4* p = reinterpret_cast<const int4*>(q) + (size_t)i * 2;
    int4 a = p[0], b = p[1];
    unsigned int d = (unsigned)(a.x & 15) | ((unsigned)(a.y & 15) << 4) |
                     ((unsigned)(a.z & 15) << 8) | ((unsigned)(a.w & 15) << 12) |
                     ((unsigned)(b.x & 15) << 16) | ((unsigned)(b.y & 15) << 20) |
                     ((unsigned)(b.z & 15) << 24) | ((unsigned)(b.w & 15) << 28);
    qp[i] = d;
  } else {
    int j = i - NDIM * KP8; // 0..262143
    float4 v = reinterpret_cast<const float4*>(A)[j];
    ushort4 o;
    o.x = f2bf(v.x); o.y = f2bf(v.y); o.z = f2bf(v.z); o.w = f2bf(v.w);
    reinterpret_cast<ushort4*>(Ab)[j] = o;
  }
}

// fallback-path A converter (exact R3 copy)
__global__ void convA_kernel(const float* __restrict__ A,
                             unsigned short* __restrict__ Ab) {
  int i = blockIdx.x * 256 + threadIdx.x;
  float4 v = reinterpret_cast<const float4*>(A)[i];
  ushort4 o;
  o.x = f2bf(v.x); o.y = f2bf(v.y); o.z = f2bf(v.z); o.w = f2bf(v.w);
  reinterpret_cast<ushort4*>(Ab)[i] = o;
}

// ---------------- R3-proven GEMM structure, PACKED-q variant -----------------
// Identical to the 49.5us/0.25-absmax kernel except: loadW reads ONE packed
// dword (was 2x int4); writeW unpacks nibbles; vmcnt ledger 5/batch -> (10).
__global__ __launch_bounds__(256, 2) void gemm_pk(
    const unsigned short* __restrict__ Ab, const unsigned int* __restrict__ qp,
    const float* __restrict__ sc, const float* __restrict__ zr,
    float* __restrict__ out) {
  __shared__ __align__(16) unsigned short A_lds[4][BM * BK]; // 64 KB
  __shared__ __align__(16) unsigned short W_lds[2][BN * BK]; // 8 KB
  __shared__ float s_lds[BN * 16];
  __shared__ float zs_lds[BN * 16]; // total 76 KB -> 2 blocks/CU

  const int tid = threadIdx.x;
  const int lane = tid & 63;
  const int wave = tid >> 6;
  const int wm = wave >> 1;
  const int wn = wave & 1;

  const int bid = blockIdx.x; // 512
  const int x = bid & 7;
  const int j = bid >> 3;
  const int r = x * 16 + (j >> 2);
  const int c = j & 3;
  const int m0 = (c & 1) * BM;
  const int ks = c >> 1;
  const int n0 = r * BN;

  for (int i = tid; i < BN * 16; i += 256) {
    int n = i >> 4;
    int g16 = i & 15;
    float s = sc[(size_t)(n0 + n) * NGRP + ks * 16 + g16];
    float z = zr[(size_t)(n0 + n) * NGRP + ks * 16 + g16];
    s_lds[i] = s;
    zs_lds[i] = z * s;
  }

  const unsigned short* Abase = Ab + (size_t)m0 * KDIM + ks * KLOC;
  const int wrow = tid >> 3; // 0..31 n-row
  const int wc = tid & 7;    // 8-k chunk
  const unsigned int* qpbase =
      qp + (size_t)(n0 + wrow) * KP8 + ks * (KLOC / 8) + wc;

  unsigned int qd[4];

  auto loadW = [&](int t, int idx) { qd[idx] = qpbase[t * 8]; };
  auto stageA = [&](int t, int b) {
#pragma unroll
    for (int i = 0; i < 4; ++i) {
      int cid = i * 256 + tid;
      int row = cid >> 3;
      int cp = cid & 7;
      int cs = cp ^ (row & 7);
      const unsigned short* g = Abase + (size_t)row * KDIM + t * BK + cs * 8;
      gl_lds16(g, &A_lds[b][(i * 256 + wave * 64) * 8]);
    }
  };
  auto writeW = [&](int t, int b, int idx) {
    int gg = t >> 1;
    float s = s_lds[wrow * 16 + gg];
    float zs = zs_lds[wrow * 16 + gg];
    unsigned int d = qd[idx];
    bf16x8 w;
#pragma unroll
    for (int jj = 0; jj < 8; ++jj)
      w[jj] = (short)f2bf(fmaf((float)((d >> (4 * jj)) & 15u), s, -zs));
    *reinterpret_cast<bf16x8*>(
        &W_lds[b][wrow * BK + ((wc ^ (wrow & 7)) << 3)]) = w;
  };

  f32x4 acc[4];
#pragma unroll
  for (int i = 0; i < 4; ++i) acc[i] = (f32x4){0.f, 0.f, 0.f, 0.f};

  const int l15 = lane & 15;
  const int lhi = lane >> 4;
  const int ar0 = wm * 64 + l15;
  const int asw = ar0 & 7;
  const int br = wn * 16 + l15;
  const int bsw = br & 7;

  auto compute = [&](int ab, int wb) {
#pragma unroll
    for (int kss = 0; kss < 2; ++kss) {
      bf16x8 bfr = *reinterpret_cast<const bf16x8*>(
          &W_lds[wb][br * BK + ((((kss << 2) + lhi) ^ bsw) << 3)]);
#pragma unroll
      for (int mi = 0; mi < 4; ++mi) {
        bf16x8 afr = *reinterpret_cast<const bf16x8*>(
            &A_lds[ab][(ar0 + mi * 16) * BK + ((((kss << 2) + lhi) ^ asw) << 3)]);
        acc[mi] = __builtin_amdgcn_mfma_f32_16x16x32_bf16(afr, bfr, acc[mi], 0, 0, 0);
      }
    }
  };

  // prologue: 3 batches in flight (5 vmem each: 1 q dword + 4 gl_lds)
  loadW(0, 0); stageA(0, 0);
  loadW(1, 1); stageA(1, 1);
  loadW(2, 2); stageA(2, 2);

  asm volatile("s_waitcnt lgkmcnt(0)" ::: "memory");
  __builtin_amdgcn_s_barrier();
  __builtin_amdgcn_sched_barrier(0);
  writeW(0, 0, 0);
  asm volatile("s_waitcnt vmcnt(10) lgkmcnt(0)" ::: "memory"); // batch0 done
  __builtin_amdgcn_s_barrier();
  __builtin_amdgcn_sched_barrier(0);

  for (int tb = 0; tb < NTL; tb += 4) {
#pragma unroll
    for (int u = 0; u < 4; ++u) {
      const int t = tb + u;
      const int tp = (t + 3 < NTL) ? (t + 3) : 0; // dummy keeps counts exact
      loadW(tp, (u + 3) & 3);
      stageA(tp, (u + 3) & 3);
      compute(u, u & 1);
      if (t + 1 < NTL) writeW(t + 1, (u + 1) & 1, (u + 1) & 3);
      asm volatile("s_waitcnt vmcnt(10) lgkmcnt(0)" ::: "memory");
      __builtin_amdgcn_s_barrier();
      __builtin_amdgcn_sched_barrier(0);
    }
  }

  const int col = n0 + wn * 16 + l15;
  const int rb = m0 + wm * 64 + (lhi << 2);
#pragma unroll
  for (int mi = 0; mi < 4; ++mi)
#pragma unroll
    for (int jj = 0; jj < 4; ++jj)
      unsafeAtomicAdd(&out[(size_t)(rb + mi * 16 + jj) * NDIM + col],
                      acc[mi][jj]);
}

// ---------------- fallback: exact R3-passed GEMM (unpacked q) ----------------
__global__ __launch_bounds__(256, 2) void gemm_r3(
    const unsigned short* __restrict__ Ab, const int* __restrict__ qw,
    const float* __restrict__ sc, const float* __restrict__ zr,
    float* __restrict__ out) {
  __shared__ __align__(16) unsigned short A_lds[4][BM * BK];
  __shared__ __align__(16) unsigned short W_lds[2][BN * BK];
  __shared__ float s_lds[BN * 16];
  __shared__ float zs_lds[BN * 16];

  const int tid = threadIdx.x;
  const int lane = tid & 63;
  const int wave = tid >> 6;
  const int wm = wave >> 1;
  const int wn = wave & 1;

  const int bid = blockIdx.x;
  const int x = bid & 7;
  const int j = bid >> 3;
  const int r = x * 16 + (j >> 2);
  const int c = j & 3;
  const int m0 = (c & 1) * BM;
  const int ks = c >> 1;
  const int n0 = r * BN;

  for (int i = tid; i < BN * 16; i += 256) {
    int n = i >> 4;
    int g16 = i & 15;
    float s = sc[(size_t)(n0 + n) * NGRP + ks * 16 + g16];
    float z = zr[(size_t)(n0 + n) * NGRP + ks * 16 + g16];
    s_lds[i] = s;
    zs_lds[i] = z * s;
  }

  const unsigned short* Abase = Ab + (size_t)m0 * KDIM + ks * KLOC;
  const int wrow = tid >> 3;
  const int wc = tid & 7;
  const int* qbase = qw + (size_t)(n0 + wrow) * KDIM + ks * KLOC + wc * 8;

  int4 qr[4][2];

  auto loadW = [&](int t, int idx) {
    const int* p = qbase + t * BK;
    qr[idx][0] = *reinterpret_cast<const int4*>(p);
    qr[idx][1] = *reinterpret_cast<const int4*>(p + 4);
  };
  auto stageA = [&](int t, int b) {
#pragma unroll
    for (int i = 0; i < 4; ++i) {
      int cid = i * 256 + tid;
      int row = cid >> 3;
      int cp = cid & 7;
      int cs = cp ^ (row & 7);
      const unsigned short* g = Abase + (size_t)row * KDIM + t * BK + cs * 8;
      gl_lds16(g, &A_lds[b][(i * 256 + wave * 64) * 8]);
    }
  };
  auto writeW = [&](int t, int b, int idx) {
    int gg = t >> 1;
    float s = s_lds[wrow * 16 + gg];
    float zs = zs_lds[wrow * 16 + gg];
    int q[8] = {qr[idx][0].x, qr[idx][0].y, qr[idx][0].z, qr[idx][0].w,
                qr[idx][1].x, qr[idx][1].y, qr[idx][1].z, qr[idx][1].w};
    bf16x8 w;
#pragma unroll
    for (int jj = 0; jj < 8; ++jj)
      w[jj] = (short)f2bf(fmaf((float)q[jj], s, -zs));
    *reinterpret_cast<bf16x8*>(
        &W_lds[b][wrow * BK + ((wc ^ (wrow & 7)) << 3)]) = w;
  };

  f32x4 acc[4];
#pragma unroll
  for (int i = 0; i < 4; ++i) acc[i] = (f32x4){0.f, 0.f, 0.f, 0.f};

  const int l15 = lane & 15;
  const int lhi = lane >> 4;
  const int ar0 = wm * 64 + l15;
  const int asw = ar0 & 7;
  const int br = wn * 16 + l15;
  const int bsw = br & 7;

  auto compute = [&](int ab, int wb) {
#pragma unroll
    for (int kss = 0; kss < 2; ++kss) {
      bf16x8 bfr = *reinterpret_cast<const bf16x8*>(
          &W_lds[wb][br * BK + ((((kss << 2) + lhi) ^ bsw) << 3)]);
#pragma unroll
      for (int mi = 0; mi < 4; ++mi) {
        bf16x8 afr = *reinterpret_cast<const bf16x8*>(
            &A_lds[ab][(ar0 + mi * 16) * BK + ((((kss << 2) + lhi) ^ asw) << 3)]);
        acc[mi] = __builtin_amdgcn_mfma_f32_16x16x32_bf16(afr, bfr, acc[mi], 0, 0, 0);
      }
    }
  };

  loadW(0, 0); stageA(0, 0);
  loadW(1, 1); stageA(1, 1);
  loadW(2, 2); stageA(2, 2);

  asm volatile("s_waitcnt lgkmcnt(0)" ::: "memory");
  __builtin_amdgcn_s_barrier();
  __builtin_amdgcn_sched_barrier(0);
  writeW(0, 0, 0);
  asm volatile("s_waitcnt vmcnt(12) lgkmcnt(0)" ::: "memory");
  __builtin_amdgcn_s_barrier();
  __builtin_amdgcn_sched_barrier(0);

  for (int tb = 0; tb < NTL; tb += 4) {
#pragma unroll
    for (int u = 0; u < 4; ++u) {
      const int t = tb + u;
      const int tp = (t + 3 < NTL) ? (t + 3) : 0;
      loadW(tp, (u + 3) & 3);
      stageA(tp, (u + 3) & 3);
      compute(u, u & 1);
      if (t + 1 < NTL) writeW(t + 1, (u + 1) & 1, (u + 1) & 3);
      asm volatile("s_waitcnt vmcnt(12) lgkmcnt(0)" ::: "memory");
      __builtin_amdgcn_s_barrier();
      __builtin_amdgcn_sched_barrier(0);
    }
  }

  const int col = n0 + wn * 16 + l15;
  const int rb = m0 + wm * 64 + (lhi << 2);
#pragma unroll
  for (int mi = 0; mi < 4; ++mi)
#pragma unroll
    for (int jj = 0; jj < 4; ++jj)
      unsafeAtomicAdd(&out[(size_t)(rb + mi * 16 + jj) * NDIM + col],
                      acc[mi][jj]);
}

extern "C" void kernel_launch(void* const* d_in, const int* in_sizes, int n_in,
                              void* d_out, int out_size, void* d_ws, size_t ws_size,
                              hipStream_t stream) {
  const float* A = (const float*)d_in[0];
  const int* qw = (const int*)d_in[1];
  const float* sc = (const float*)d_in[2];
  const float* zr = (const float*)d_in[3];
  float* out = (float*)d_out;

  hipMemsetAsync(d_out, 0, (size_t)MDIM * NDIM * sizeof(float), stream);

  if (ws_size >= (10u << 20)) {
    // packed path: Ab 2MB @0, qp 8MB @2MB
    unsigned short* Ab = (unsigned short*)d_ws;
    unsigned int* qp = (unsigned int*)((char*)d_ws + (2u << 20));
    prep_kernel<<<9216, 256, 0, stream>>>(A, qw, Ab, qp);
    gemm_pk<<<(MDIM / BM) * (NDIM / BN) * SPLITK, 256, 0, stream>>>(
        Ab, qp, sc, zr, out);
  } else {
    // fallback: exact R3-proven path (needs only 2MB)
    unsigned short* Ab = (unsigned short*)d_ws;
    convA_kernel<<<(MDIM * KDIM / 4) / 256, 256, 0, stream>>>(A, Ab);
    gemm_r3<<<(MDIM / BM) * (NDIM / BN) * SPLITK, 256, 0, stream>>>(
        Ab, qw, sc, zr, out);
  }
}

// Round 8
// 129.636 us; speedup vs baseline: 1.0925x; 1.0378x over previous
//
#include <hip/hip_runtime.h>

typedef __attribute__((ext_vector_type(8))) short bf16x8;
typedef __attribute__((ext_vector_type(4))) float f32x4;

#define MDIM 256
#define NDIM 4096
#define KDIM 4096
#define KP8 (KDIM / 8) /* 512 packed dwords per n-row */
#define NGRP 32

typedef const __attribute__((address_space(1))) void* gas_ptr;
typedef __attribute__((address_space(3))) void* las_ptr;

__device__ __forceinline__ unsigned short f2bf(float f) {
  union { float f; unsigned int u; } v;
  v.f = f;
  unsigned int r = v.u + 0x7FFFu + ((v.u >> 16) & 1u); // RNE
  return (unsigned short)(r >> 16);
}

__device__ __forceinline__ void gl_lds16(const void* g, void* l) {
  __builtin_amdgcn_global_load_lds((gas_ptr)g, (las_ptr)l, 16, 0, 0);
}

// ---------------- prep: pack q to nibbles (64->8 MB) + A fp32->bf16 ----------
__global__ void prep_kernel(const float* __restrict__ A, const int* __restrict__ q,
                            unsigned short* __restrict__ Ab,
                            unsigned int* __restrict__ qp) {
  int i = blockIdx.x * 256 + threadIdx.x; // grid 9216*256 = 2359296 exact
  if (i < NDIM * KP8) { // 2097152 pack threads, 32B in / 4B out
    const int4* p = reinterpret_cast<const int4*>(q) + (size_t)i * 2;
    int4 a = p[0], b = p[1];
    unsigned int d = (unsigned)(a.x & 15) | ((unsigned)(a.y & 15) << 4) |
                     ((unsigned)(a.z & 15) << 8) | ((unsigned)(a.w & 15) << 12) |
                     ((unsigned)(b.x & 15) << 16) | ((unsigned)(b.y & 15) << 20) |
                     ((unsigned)(b.z & 15) << 24) | ((unsigned)(b.w & 15) << 28);
    qp[i] = d;
  } else {
    int j = i - NDIM * KP8; // 0..262143
    float4 v = reinterpret_cast<const float4*>(A)[j];
    ushort4 o;
    o.x = f2bf(v.x); o.y = f2bf(v.y); o.z = f2bf(v.z); o.w = f2bf(v.w);
    reinterpret_cast<ushort4*>(Ab)[j] = o;
  }
}

// ---------------- big-tile GEMM: BM=256, BN=64, BK=64, 8 waves --------------
// Same proven 2-barrier pipeline/ledger as R7's gemm_pk (5 vmem/batch/wave,
// 4-deep A slots, 3-ahead issue, drain vmcnt(10)); tile doubled in M and N to
// amortize the measured ~1400cy fixed per-iteration cost. 1 block/CU.
#define BM 256
#define BN 64
#define BK 64
#define SPLITK 4
#define KLOC (KDIM / SPLITK) /* 1024 */
#define NTL (KLOC / BK)      /* 16 */
#define GPS (KLOC / 128)     /* 8 groups per split */

__global__ __launch_bounds__(512, 1) void gemm_big(
    const unsigned short* __restrict__ Ab, const unsigned int* __restrict__ qp,
    const float* __restrict__ sc, const float* __restrict__ zr,
    float* __restrict__ out) {
  __shared__ __align__(16) unsigned short A_lds[4][BM * BK]; // 4 x 32 KB
  __shared__ __align__(16) unsigned short W_lds[2][BN * BK]; // 2 x 8 KB
  __shared__ float s_lds[BN * GPS];   // 2 KB
  __shared__ float zs_lds[BN * GPS];  // 2 KB   total 148 KB -> 1 block/CU

  const int tid = threadIdx.x;
  const int lane = tid & 63;
  const int wave = tid >> 6;      // 0..7
  const int wm = wave >> 1;       // 0..3 -> 64 rows each
  const int wn = wave & 1;        // 0..1 -> 32 cols each

  // XCD swizzle: grid 256. Each XCD: 4 k-splits x 8 n-ranges; the 8 blocks
  // sharing one A k-slice (512 KB) are co-XCD -> A L2-hits after first touch.
  const int bid = blockIdx.x;
  const int xcd = bid & 7;
  const int j = bid >> 3;        // 0..31
  const int ks = j >> 3;         // 0..3
  const int nl = j & 7;
  const int n0 = (xcd * 8 + nl) * BN; // 0..4032
  const int kbase = ks * KLOC;

  // stage (s, z*s): 64 rows x 8 groups = 512 = exactly one pass
  {
    int n = tid >> 3, g = tid & 7;
    float s = sc[(size_t)(n0 + n) * NGRP + ks * GPS + g];
    float z = zr[(size_t)(n0 + n) * NGRP + ks * GPS + g];
    s_lds[tid] = s;
    zs_lds[tid] = z * s;
  }

  const unsigned short* Abase = Ab + kbase;
  const int wrow = tid >> 3; // 0..63 (n-row for W staging)
  const int wc = tid & 7;    // 8-dword chunk column
  const unsigned int* qpbase = qp + (size_t)(n0 + wrow) * KP8 + (kbase >> 3) + wc;

  unsigned int qd[4];

  auto loadW = [&](int t, int idx) { qd[idx] = qpbase[t * 8]; };
  // A tile 256x64 bf16 = 2048 x 16B chunks; 512 threads x 4 gl_lds.
  // Linear LDS dest; XOR-swizzled global SOURCE (rule 21).
  auto stageA = [&](int t, int b) {
#pragma unroll
    for (int i = 0; i < 4; ++i) {
      int cid = i * 512 + tid;
      int row = cid >> 3;
      int cp = cid & 7;
      int cs = cp ^ (row & 7);
      const unsigned short* g = Abase + (size_t)row * KDIM + t * BK + cs * 8;
      gl_lds16(g, &A_lds[b][(i * 512 + wave * 64) * 8]); // wave-uniform base
    }
  };
  auto writeW = [&](int t, int b, int idx) {
    int gg = t >> 1; // BK=64: tile t in local group t>>1
    float s = s_lds[wrow * GPS + gg];
    float zs = zs_lds[wrow * GPS + gg];
    unsigned int d = qd[idx];
    bf16x8 w;
#pragma unroll
    for (int jj = 0; jj < 8; ++jj)
      w[jj] = (short)f2bf(fmaf((float)((d >> (4 * jj)) & 15u), s, -zs));
    *reinterpret_cast<bf16x8*>(
        &W_lds[b][wrow * BK + ((wc ^ (wrow & 7)) << 3)]) = w;
  };

  f32x4 acc[4][2];
#pragma unroll
  for (int i = 0; i < 4; ++i)
#pragma unroll
    for (int n = 0; n < 2; ++n) acc[i][n] = (f32x4){0.f, 0.f, 0.f, 0.f};

  const int l15 = lane & 15;
  const int lhi = lane >> 4;
  const int ar0 = wm * 64 + l15;  // 0..255
  const int asw = ar0 & 7;

  auto compute = [&](int ab, int wb) {
#pragma unroll
    for (int kss = 0; kss < 2; ++kss) {
#pragma unroll
      for (int ni = 0; ni < 2; ++ni) {
        const int br = wn * 32 + ni * 16 + l15; // 0..63
        bf16x8 bfr = *reinterpret_cast<const bf16x8*>(
            &W_lds[wb][br * BK + ((((kss << 2) + lhi) ^ (br & 7)) << 3)]);
#pragma unroll
        for (int mi = 0; mi < 4; ++mi) {
          bf16x8 afr = *reinterpret_cast<const bf16x8*>(
              &A_lds[ab][(ar0 + mi * 16) * BK +
                         ((((kss << 2) + lhi) ^ asw) << 3)]);
          acc[mi][ni] = __builtin_amdgcn_mfma_f32_16x16x32_bf16(
              afr, bfr, acc[mi][ni], 0, 0, 0);
        }
      }
    }
  };

  // prologue: 3 batches in flight (5 vmem each: 1 q dword + 4 gl_lds)
  loadW(0, 0); stageA(0, 0);
  loadW(1, 1); stageA(1, 1);
  loadW(2, 2); stageA(2, 2);

  asm volatile("s_waitcnt lgkmcnt(0)" ::: "memory"); // s/zs stores done
  __builtin_amdgcn_s_barrier();
  __builtin_amdgcn_sched_barrier(0);
  writeW(0, 0, 0); // compiler inserts precise vmcnt for qd[0]
  asm volatile("s_waitcnt vmcnt(10) lgkmcnt(0)" ::: "memory"); // batch0 done
  __builtin_amdgcn_s_barrier();
  __builtin_amdgcn_sched_barrier(0);

  // main loop: NTL=16, unroll-4, 3-ahead issue, never drain vmcnt to 0
  for (int tb = 0; tb < NTL; tb += 4) {
#pragma unroll
    for (int u = 0; u < 4; ++u) {
      const int t = tb + u;
      const int tp = (t + 3 < NTL) ? (t + 3) : 0; // dummy keeps counts exact
      loadW(tp, (u + 3) & 3);
      stageA(tp, (u + 3) & 3);
      compute(u, u & 1);
      if (t + 1 < NTL) writeW(t + 1, (u + 1) & 1, (u + 1) & 3);
      asm volatile("s_waitcnt vmcnt(10) lgkmcnt(0)" ::: "memory");
      __builtin_amdgcn_s_barrier();
      __builtin_amdgcn_sched_barrier(0);
    }
  }

  // epilogue: D col=lane&15 (+ni*16), row=4*lhi+j (+mi*16); split-K atomic add
  const int col = n0 + wn * 32 + l15;
  const int rb = wm * 64 + (lhi << 2);
#pragma unroll
  for (int mi = 0; mi < 4; ++mi)
#pragma unroll
    for (int ni = 0; ni < 2; ++ni)
#pragma unroll
      for (int jj = 0; jj < 4; ++jj)
        unsafeAtomicAdd(&out[(size_t)(rb + mi * 16 + jj) * NDIM + col + ni * 16],
                        acc[mi][ni][jj]);
}

// ---------------- fallback (ws too small): exact R3-proven path --------------
#define FBM 128
#define FBN 32
#define FSPLITK 2
#define FKLOC (KDIM / FSPLITK)
#define FNTL (FKLOC / BK)

__global__ void convA_kernel(const float* __restrict__ A,
                             unsigned short* __restrict__ Ab) {
  int i = blockIdx.x * 256 + threadIdx.x;
  float4 v = reinterpret_cast<const float4*>(A)[i];
  ushort4 o;
  o.x = f2bf(v.x); o.y = f2bf(v.y); o.z = f2bf(v.z); o.w = f2bf(v.w);
  reinterpret_cast<ushort4*>(Ab)[i] = o;
}

__global__ __launch_bounds__(256, 2) void gemm_r3(
    const unsigned short* __restrict__ Ab, const int* __restrict__ qw,
    const float* __restrict__ sc, const float* __restrict__ zr,
    float* __restrict__ out) {
  __shared__ __align__(16) unsigned short A_lds[4][FBM * BK];
  __shared__ __align__(16) unsigned short W_lds[2][FBN * BK];
  __shared__ float s_lds[FBN * 16];
  __shared__ float zs_lds[FBN * 16];

  const int tid = threadIdx.x;
  const int lane = tid & 63;
  const int wave = tid >> 6;
  const int wm = wave >> 1;
  const int wn = wave & 1;

  const int bid = blockIdx.x;
  const int x = bid & 7;
  const int j = bid >> 3;
  const int r = x * 16 + (j >> 2);
  const int c = j & 3;
  const int m0 = (c & 1) * FBM;
  const int ks = c >> 1;
  const int n0 = r * FBN;

  for (int i = tid; i < FBN * 16; i += 256) {
    int n = i >> 4;
    int g16 = i & 15;
    float s = sc[(size_t)(n0 + n) * NGRP + ks * 16 + g16];
    float z = zr[(size_t)(n0 + n) * NGRP + ks * 16 + g16];
    s_lds[i] = s;
    zs_lds[i] = z * s;
  }

  const unsigned short* Abase = Ab + (size_t)m0 * KDIM + ks * FKLOC;
  const int wrow = tid >> 3;
  const int wc = tid & 7;
  const int* qbase = qw + (size_t)(n0 + wrow) * KDIM + ks * FKLOC + wc * 8;

  int4 qr[4][2];

  auto loadW = [&](int t, int idx) {
    const int* p = qbase + t * BK;
    qr[idx][0] = *reinterpret_cast<const int4*>(p);
    qr[idx][1] = *reinterpret_cast<const int4*>(p + 4);
  };
  auto stageA = [&](int t, int b) {
#pragma unroll
    for (int i = 0; i < 4; ++i) {
      int cid = i * 256 + tid;
      int row = cid >> 3;
      int cp = cid & 7;
      int cs = cp ^ (row & 7);
      const unsigned short* g = Abase + (size_t)row * KDIM + t * BK + cs * 8;
      gl_lds16(g, &A_lds[b][(i * 256 + wave * 64) * 8]);
    }
  };
  auto writeW = [&](int t, int b, int idx) {
    int gg = t >> 1;
    float s = s_lds[wrow * 16 + gg];
    float zs = zs_lds[wrow * 16 + gg];
    int q[8] = {qr[idx][0].x, qr[idx][0].y, qr[idx][0].z, qr[idx][0].w,
                qr[idx][1].x, qr[idx][1].y, qr[idx][1].z, qr[idx][1].w};
    bf16x8 w;
#pragma unroll
    for (int jj = 0; jj < 8; ++jj)
      w[jj] = (short)f2bf(fmaf((float)q[jj], s, -zs));
    *reinterpret_cast<bf16x8*>(
        &W_lds[b][wrow * BK + ((wc ^ (wrow & 7)) << 3)]) = w;
  };

  f32x4 acc[4];
#pragma unroll
  for (int i = 0; i < 4; ++i) acc[i] = (f32x4){0.f, 0.f, 0.f, 0.f};

  const int l15 = lane & 15;
  const int lhi = lane >> 4;
  const int ar0 = wm * 64 + l15;
  const int asw = ar0 & 7;
  const int br = wn * 16 + l15;
  const int bsw = br & 7;

  auto compute = [&](int ab, int wb) {
#pragma unroll
    for (int kss = 0; kss < 2; ++kss) {
      bf16x8 bfr = *reinterpret_cast<const bf16x8*>(
          &W_lds[wb][br * BK + ((((kss << 2) + lhi) ^ bsw) << 3)]);
#pragma unroll
      for (int mi = 0; mi < 4; ++mi) {
        bf16x8 afr = *reinterpret_cast<const bf16x8*>(
            &A_lds[ab][(ar0 + mi * 16) * BK + ((((kss << 2) + lhi) ^ asw) << 3)]);
        acc[mi] = __builtin_amdgcn_mfma_f32_16x16x32_bf16(afr, bfr, acc[mi], 0, 0, 0);
      }
    }
  };

  loadW(0, 0); stageA(0, 0);
  loadW(1, 1); stageA(1, 1);
  loadW(2, 2); stageA(2, 2);

  asm volatile("s_waitcnt lgkmcnt(0)" ::: "memory");
  __builtin_amdgcn_s_barrier();
  __builtin_amdgcn_sched_barrier(0);
  writeW(0, 0, 0);
  asm volatile("s_waitcnt vmcnt(12) lgkmcnt(0)" ::: "memory");
  __builtin_amdgcn_s_barrier();
  __builtin_amdgcn_sched_barrier(0);

  for (int tb = 0; tb < FNTL; tb += 4) {
#pragma unroll
    for (int u = 0; u < 4; ++u) {
      const int t = tb + u;
      const int tp = (t + 3 < FNTL) ? (t + 3) : 0;
      loadW(tp, (u + 3) & 3);
      stageA(tp, (u + 3) & 3);
      compute(u, u & 1);
      if (t + 1 < FNTL) writeW(t + 1, (u + 1) & 1, (u + 1) & 3);
      asm volatile("s_waitcnt vmcnt(12) lgkmcnt(0)" ::: "memory");
      __builtin_amdgcn_s_barrier();
      __builtin_amdgcn_sched_barrier(0);
    }
  }

  const int col = n0 + wn * 16 + l15;
  const int rb = m0 + wm * 64 + (lhi << 2);
#pragma unroll
  for (int mi = 0; mi < 4; ++mi)
#pragma unroll
    for (int jj = 0; jj < 4; ++jj)
      unsafeAtomicAdd(&out[(size_t)(rb + mi * 16 + jj) * NDIM + col],
                      acc[mi][jj]);
}

extern "C" void kernel_launch(void* const* d_in, const int* in_sizes, int n_in,
                              void* d_out, int out_size, void* d_ws, size_t ws_size,
                              hipStream_t stream) {
  const float* A = (const float*)d_in[0];
  const int* qw = (const int*)d_in[1];
  const float* sc = (const float*)d_in[2];
  const float* zr = (const float*)d_in[3];
  float* out = (float*)d_out;

  hipMemsetAsync(d_out, 0, (size_t)MDIM * NDIM * sizeof(float), stream);

  if (ws_size >= (10u << 20)) {
    // packed path: Ab 2MB @0, qp 8MB @2MB  (ws verified 256 MiB on this rig)
    unsigned short* Ab = (unsigned short*)d_ws;
    unsigned int* qp = (unsigned int*)((char*)d_ws + (2u << 20));
    prep_kernel<<<9216, 256, 0, stream>>>(A, qw, Ab, qp);
    gemm_big<<<(NDIM / BN) * SPLITK, 512, 0, stream>>>(Ab, qp, sc, zr, out);
  } else {
    // fallback: exact R3-proven path (needs only 2MB)
    unsigned short* Ab = (unsigned short*)d_ws;
    convA_kernel<<<(MDIM * KDIM / 4) / 256, 256, 0, stream>>>(A, Ab);
    gemm_r3<<<(MDIM / FBM) * (NDIM / FBN) * FSPLITK, 256, 0, stream>>>(
        Ab, qw, sc, zr, out);
  }
}